// Round 1
// baseline (80.455 us; speedup 1.0000x reference)
//
#include <hip/hip_runtime.h>
#include <hip/hip_bf16.h>

// y = (x * (255/q[c]) + noise) * (q[c]/255)
// x, noise, y: (N=32, C=64, H=128, W=128) fp32, contiguous.
// q: 64 fp32 per-channel table.
// Elementwise, memory-bound. float4 vectorization: HW = 16384 elements per
// channel block, divisible by 4, so each float4 lies in a single channel.
// channel of float4 index i4: (i4*4 >> 14) & 63 == (i4 >> 12) & 63.

__global__ __launch_bounds__(256) void redmarkjpeg_kernel(
    const float4* __restrict__ x,
    const float*  __restrict__ q,
    const float4* __restrict__ noise,
    float4* __restrict__ out,
    int n4)
{
    int i = blockIdx.x * blockDim.x + threadIdx.x;
    const int stride = gridDim.x * blockDim.x;
    for (; i < n4; i += stride) {
        const int c = (i >> 12) & 63;
        const float qv = q[c];
        const float r = 255.0f / qv;   // matches ref: x * (255/q)
        const float s = qv / 255.0f;   // matches ref: * (q/255)
        const float4 xv = x[i];
        const float4 nv = noise[i];
        float4 o;
        o.x = (xv.x * r + nv.x) * s;
        o.y = (xv.y * r + nv.y) * s;
        o.z = (xv.z * r + nv.z) * s;
        o.w = (xv.w * r + nv.w) * s;
        out[i] = o;
    }
}

extern "C" void kernel_launch(void* const* d_in, const int* in_sizes, int n_in,
                              void* d_out, int out_size, void* d_ws, size_t ws_size,
                              hipStream_t stream)
{
    const float4* x     = (const float4*)d_in[0];
    const float*  q     = (const float*)d_in[1];
    const float4* noise = (const float4*)d_in[2];
    float4*       out   = (float4*)d_out;

    const int n4 = out_size / 4;        // 33,554,432 / 4 = 8,388,608
    const int block = 256;
    int grid = (n4 + block - 1) / block;
    if (grid > 2048) grid = 2048;       // grid-stride the rest
    redmarkjpeg_kernel<<<grid, block, 0, stream>>>(x, q, noise, out, n4);
}

// Round 3
// 62.497 us; speedup vs baseline: 1.2873x; 1.2873x over previous
//
#include <hip/hip_runtime.h>
#include <hip/hip_bf16.h>

// y = (x * (255/q[c]) + noise) * (q[c]/255)
// x, noise, y: (N=32, C=64, H=128, W=128) fp32, contiguous. q: 64 fp32.
// channel of float4 index i4: (i4 >> 12) & 63  (HW=16384 elems = 4096 float4s).
//
// Memory-bound. Inputs = 268 MB, output = 134 MB, L3 = 256 MiB.
// Non-temporal stores keep the streamed output from evicting inputs out of
// L3 across graph replays; inputs then mostly L3-hit.

typedef float vfloat4 __attribute__((ext_vector_type(4)));

__global__ __launch_bounds__(256) void redmarkjpeg_kernel(
    const vfloat4* __restrict__ x,
    const float*   __restrict__ q,
    const vfloat4* __restrict__ noise,
    vfloat4* __restrict__ out,
    int n4)
{
    constexpr int U = 4;
    const int tid    = blockIdx.x * blockDim.x + threadIdx.x;
    const int stride = gridDim.x * blockDim.x;

    int     idx[U];
    vfloat4 xv[U], nv[U];
    bool    ok[U];

    #pragma unroll
    for (int k = 0; k < U; ++k) {
        idx[k] = tid + k * stride;
        ok[k]  = idx[k] < n4;
    }
    // Issue all loads first (independent -> 8 loads in flight per thread).
    #pragma unroll
    for (int k = 0; k < U; ++k) {
        if (ok[k]) { xv[k] = x[idx[k]]; nv[k] = noise[idx[k]]; }
    }
    #pragma unroll
    for (int k = 0; k < U; ++k) {
        if (ok[k]) {
            const int c = (idx[k] >> 12) & 63;
            const float qv = q[c];
            const float r  = 255.0f / qv;
            const float s  = qv / 255.0f;
            vfloat4 o;
            o.x = (xv[k].x * r + nv[k].x) * s;
            o.y = (xv[k].y * r + nv[k].y) * s;
            o.z = (xv[k].z * r + nv[k].z) * s;
            o.w = (xv[k].w * r + nv[k].w) * s;
            __builtin_nontemporal_store(o, &out[idx[k]]);
        }
    }
}

extern "C" void kernel_launch(void* const* d_in, const int* in_sizes, int n_in,
                              void* d_out, int out_size, void* d_ws, size_t ws_size,
                              hipStream_t stream)
{
    const vfloat4* x     = (const vfloat4*)d_in[0];
    const float*   q     = (const float*)d_in[1];
    const vfloat4* noise = (const vfloat4*)d_in[2];
    vfloat4*       out   = (vfloat4*)d_out;

    const int n4 = out_size / 4;                 // 8,388,608
    const int block = 256;
    constexpr int U = 4;
    const int grid = (n4 + block * U - 1) / (block * U);  // 8192 blocks
    redmarkjpeg_kernel<<<grid, block, 0, stream>>>(x, q, noise, out, n4);
}